// Round 1
// baseline (384.024 us; speedup 1.0000x reference)
//
#include <hip/hip_runtime.h>
#include <stdint.h>

typedef unsigned short u16;
typedef __attribute__((ext_vector_type(8))) short short8;
typedef __attribute__((ext_vector_type(4))) float f32x4;
typedef __attribute__((ext_vector_type(8))) u16 u16x8;

#define LOG2E 1.4426950408889634f
// 2*SCALE/SOFT_CAP*log2(e) = 2*0.125/50*1.4426950408889634
#define CEXP2 0.0072134752044448f

static __device__ __forceinline__ u16 f2bf(float f) {
  union { float f; unsigned u; } v; v.f = f;
  unsigned r = v.u + 0x7fffu + ((v.u >> 16) & 1u);
  return (u16)(r >> 16);
}

static __device__ __forceinline__ void gload16(const void* g, void* l) {
  __builtin_amdgcn_global_load_lds(
      (const __attribute__((address_space(1))) void*)g,
      (__attribute__((address_space(3))) void*)l, 16, 0, 0);
}

// ---------------- cast x fp32 -> bf16 ----------------
__global__ void __launch_bounds__(256) cast_x_kernel(const float* __restrict__ x,
                                                     u16* __restrict__ xb, int n) {
  int i = (blockIdx.x * 256 + threadIdx.x) * 8;
  if (i >= n) return;
  f32x4 a = *(const f32x4*)(x + i);
  f32x4 b = *(const f32x4*)(x + i + 4);
  u16x8 o;
  o[0] = f2bf(a[0]); o[1] = f2bf(a[1]); o[2] = f2bf(a[2]); o[3] = f2bf(a[3]);
  o[4] = f2bf(b[0]); o[5] = f2bf(b[1]); o[6] = f2bf(b[2]); o[7] = f2bf(b[3]);
  *(u16x8*)(xb + i) = o;
}

// ------- transpose+cast weight: W (1024 x ncols) fp32 -> WT bf16, WT[row_off+n][k] -------
__global__ void __launch_bounds__(256) wtrans_kernel(const float* __restrict__ W,
                                                     u16* __restrict__ WT,
                                                     int ncols, int row_off) {
  __shared__ u16 tile[64][68];
  int c0 = blockIdx.x * 64;
  int r0 = blockIdx.y * 64;
  int cc = threadIdx.x & 63, rb = threadIdx.x >> 6;
#pragma unroll
  for (int i = 0; i < 16; i++) {
    int r = rb + i * 4;
    tile[r][cc] = f2bf(W[(size_t)(r0 + r) * ncols + c0 + cc]);
  }
  __syncthreads();
#pragma unroll
  for (int i = 0; i < 16; i++) {
    int n = rb + i * 4;
    WT[(size_t)(row_off + c0 + n) * 1024 + r0 + cc] = tile[cc][n];
  }
}

// ---------------- GEMM: C(MxN) fp32 = A(MxK) bf16 @ Bt(NxK)^T bf16 ----------------
// 128x128 tile, BK=64, 4 waves (2x2), each wave 64x64 = 4x4 fragments.
__global__ void __launch_bounds__(256) gemm_bt_kernel(const u16* __restrict__ A,
                                                      const u16* __restrict__ Bt,
                                                      float* __restrict__ C,
                                                      int M, int N, int K) {
  __shared__ __align__(16) u16 ldsA[128 * 64];
  __shared__ __align__(16) u16 ldsB[128 * 64];
  int tid = threadIdx.x;
  int l = tid & 63, w = tid >> 6;
  int wm = w >> 1, wn = w & 1;
  int fr = l & 15, fg = l >> 4;
  int m0 = blockIdx.y * 128, n0 = blockIdx.x * 128;
  f32x4 acc[4][4];
#pragma unroll
  for (int i = 0; i < 4; i++)
#pragma unroll
    for (int j = 0; j < 4; j++) acc[i][j] = (f32x4)(0.0f);

  int lrow = l >> 3;         // 0..7 row within 8-row chunk
  int lcol = (l & 7) * 8;    // element offset within 64-elem row
  for (int k0 = 0; k0 < K; k0 += 64) {
#pragma unroll
    for (int i = 0; i < 4; i++) {
      int ci = w * 4 + i;  // chunk id 0..15, covers 8 rows each
      gload16(A + (size_t)(m0 + ci * 8 + lrow) * K + k0 + lcol, ldsA + ci * 512);
      gload16(Bt + (size_t)(n0 + ci * 8 + lrow) * K + k0 + lcol, ldsB + ci * 512);
    }
    __syncthreads();
#pragma unroll
    for (int ks = 0; ks < 2; ks++) {
      short8 av[4], bv[4];
#pragma unroll
      for (int mb = 0; mb < 4; mb++)
        av[mb] = *(const short8*)(ldsA + (wm * 64 + mb * 16 + fr) * 64 + ks * 32 + fg * 8);
#pragma unroll
      for (int nb = 0; nb < 4; nb++)
        bv[nb] = *(const short8*)(ldsB + (wn * 64 + nb * 16 + fr) * 64 + ks * 32 + fg * 8);
#pragma unroll
      for (int mb = 0; mb < 4; mb++)
#pragma unroll
        for (int nb = 0; nb < 4; nb++)
          acc[mb][nb] = __builtin_amdgcn_mfma_f32_16x16x32_bf16(av[mb], bv[nb], acc[mb][nb], 0, 0, 0);
    }
    __syncthreads();
  }
#pragma unroll
  for (int mb = 0; mb < 4; mb++)
#pragma unroll
    for (int nb = 0; nb < 4; nb++)
#pragma unroll
      for (int r = 0; r < 4; r++)
        C[(size_t)(m0 + wm * 64 + mb * 16 + fg * 4 + r) * N + (n0 + wn * 64 + nb * 16 + fr)] =
            acc[mb][nb][r];
}

// ---------------- QKNorm + layout: qkv fp32 [4096][1536] -> Qn/Kn bf16, Vt bf16 transposed ----------------
__global__ void __launch_bounds__(256) qknorm_kernel(const float* __restrict__ qkv,
                                                     const float* __restrict__ qw,
                                                     const float* __restrict__ kw,
                                                     u16* __restrict__ Qn,
                                                     u16* __restrict__ Kn,
                                                     u16* __restrict__ Vt) {
  int task = blockIdx.x * 4 + (threadIdx.x >> 6);
  int d = threadIdx.x & 63;
  int tf = task / 20, slot = task - (task / 20) * 20;
  int b = tf >> 11, t = tf & 2047;
  if (slot < 16) {
    float v = qkv[(size_t)tf * 1536 + slot * 64 + d];
    float ss = v * v;
#pragma unroll
    for (int m = 32; m >= 1; m >>= 1) ss += __shfl_xor(ss, m, 64);
    float rn = rsqrtf(ss * (1.0f / 64.0f) + 1e-6f);
    Qn[(size_t)((b * 16 + slot) * 2048 + t) * 64 + d] = f2bf(v * rn * qw[d]);
  } else {
    int kv = slot - 16;
    float v = qkv[(size_t)tf * 1536 + 1024 + kv * 64 + d];
    float ss = v * v;
#pragma unroll
    for (int m = 32; m >= 1; m >>= 1) ss += __shfl_xor(ss, m, 64);
    float rn = rsqrtf(ss * (1.0f / 64.0f) + 1e-6f);
    Kn[(size_t)((b * 4 + kv) * 2048 + t) * 64 + d] = f2bf(v * rn * kw[d]);
    float vv = qkv[(size_t)tf * 1536 + 1280 + kv * 64 + d];
    Vt[((size_t)((b * 4 + kv) * 64 + d)) * 2048 + t] = f2bf(vv);
  }
}

// ---------------- Flash attention with tanh soft-cap, GQA, causal ----------------
// Grid: 1024 = 32 heads * 32 qtiles. Block 256 = 4 waves, each wave owns 16 q-rows.
__global__ void __launch_bounds__(256) attn_kernel(const u16* __restrict__ Qn,
                                                   const u16* __restrict__ Kn,
                                                   const u16* __restrict__ Vt,
                                                   u16* __restrict__ AO) {
  __shared__ __align__(16) u16 plds[4][16][88];
  int w = threadIdx.x >> 6, l = threadIdx.x & 63;
  int fr = l & 15, fg = l >> 4;
  int qtile = blockIdx.x & 31;
  int head = blockIdx.x >> 5;
  int b = head >> 4, h = head & 15;
  int kvh = h >> 2;  // G = 4
  const u16* Qb = Qn + (size_t)((b * 16 + h) * 2048) * 64;
  const u16* Kb = Kn + (size_t)((b * 4 + kvh) * 2048) * 64;
  const u16* Vb = Vt + (size_t)((b * 4 + kvh) * 64) * 2048;
  int qt0 = qtile * 64 + w * 16;

  short8 qf[2];
#pragma unroll
  for (int ks = 0; ks < 2; ks++)
    qf[ks] = *(const short8*)(Qb + (size_t)(qt0 + fr) * 64 + ks * 32 + fg * 8);

  f32x4 of[4];
#pragma unroll
  for (int i = 0; i < 4; i++) of[i] = (f32x4)(0.0f);
  float mrow[4] = {-1e30f, -1e30f, -1e30f, -1e30f};
  float lsum[4] = {0.0f, 0.0f, 0.0f, 0.0f};
  u16(*P)[88] = plds[w];

  for (int t = 0; t <= qtile; t++) {
    int kb0 = t * 64;
    f32x4 sf[4];
#pragma unroll
    for (int kb = 0; kb < 4; kb++) sf[kb] = (f32x4)(0.0f);
    // S = Q K^T  (A = Q rows, B = K rows as B^T cols; identical frag pattern)
#pragma unroll
    for (int ks = 0; ks < 2; ks++) {
#pragma unroll
      for (int kb = 0; kb < 4; kb++) {
        short8 kf = *(const short8*)(Kb + (size_t)(kb0 + kb * 16 + fr) * 64 + ks * 32 + fg * 8);
        sf[kb] = __builtin_amdgcn_mfma_f32_16x16x32_bf16(qf[ks], kf, sf[kb], 0, 0, 0);
      }
    }
    // soft cap: logit = 50*tanh(s*SCALE/50) = 50 - 100/(exp2(s*CEXP2)+1)
#pragma unroll
    for (int kb = 0; kb < 4; kb++)
#pragma unroll
      for (int r = 0; r < 4; r++) {
        float e = __builtin_amdgcn_exp2f(sf[kb][r] * CEXP2);
        sf[kb][r] = 50.0f - 100.0f * __builtin_amdgcn_rcpf(e + 1.0f);
      }
    // causal mask (only diagonal tile is partial)
    if (t == qtile) {
#pragma unroll
      for (int kb = 0; kb < 4; kb++)
#pragma unroll
        for (int r = 0; r < 4; r++)
          if (kb0 + kb * 16 + fr > qt0 + fg * 4 + r) sf[kb][r] = -1e30f;
    }
    // online softmax; row q = fg*4+r, cols kk across (kb, fr). Reduce over low-4 lane bits.
#pragma unroll
    for (int r = 0; r < 4; r++) {
      float mx = fmaxf(fmaxf(sf[0][r], sf[1][r]), fmaxf(sf[2][r], sf[3][r]));
      mx = fmaxf(mx, __shfl_xor(mx, 1, 64));
      mx = fmaxf(mx, __shfl_xor(mx, 2, 64));
      mx = fmaxf(mx, __shfl_xor(mx, 4, 64));
      mx = fmaxf(mx, __shfl_xor(mx, 8, 64));
      float mnew = fmaxf(mrow[r], mx);
      float alpha = __builtin_amdgcn_exp2f((mrow[r] - mnew) * LOG2E);
      mrow[r] = mnew;
      float rs = 0.0f;
#pragma unroll
      for (int kb = 0; kb < 4; kb++) {
        float pf = __builtin_amdgcn_exp2f((sf[kb][r] - mnew) * LOG2E);
        sf[kb][r] = pf;
        rs += pf;
      }
      rs += __shfl_xor(rs, 1, 64);
      rs += __shfl_xor(rs, 2, 64);
      rs += __shfl_xor(rs, 4, 64);
      rs += __shfl_xor(rs, 8, 64);
      lsum[r] = lsum[r] * alpha + rs;
#pragma unroll
      for (int db = 0; db < 4; db++) of[db][r] *= alpha;
    }
    // P (C-frag layout) -> per-wave LDS -> A-frag layout. Wave-private: no barrier needed.
#pragma unroll
    for (int kb = 0; kb < 4; kb++)
#pragma unroll
      for (int r = 0; r < 4; r++)
        P[fg * 4 + r][kb * 16 + fr] = f2bf(sf[kb][r]);
    short8 pa[2];
#pragma unroll
    for (int ks = 0; ks < 2; ks++)
      pa[ks] = *(const short8*)(&P[fr][ks * 32 + fg * 8]);
    // O += P @ V  (B-frag reads Vt[d][kk], contiguous in kk)
#pragma unroll
    for (int ks = 0; ks < 2; ks++)
#pragma unroll
      for (int db = 0; db < 4; db++) {
        short8 vf = *(const short8*)(Vb + (size_t)(db * 16 + fr) * 2048 + kb0 + ks * 32 + fg * 8);
        of[db] = __builtin_amdgcn_mfma_f32_16x16x32_bf16(pa[ks], vf, of[db], 0, 0, 0);
      }
  }
#pragma unroll
  for (int r = 0; r < 4; r++) lsum[r] = 1.0f / lsum[r];
#pragma unroll
  for (int db = 0; db < 4; db++)
#pragma unroll
    for (int r = 0; r < 4; r++)
      AO[(size_t)(b * 2048 + qt0 + fg * 4 + r) * 1024 + h * 64 + db * 16 + fr] =
          f2bf(of[db][r] * lsum[r]);
}

extern "C" void kernel_launch(void* const* d_in, const int* in_sizes, int n_in,
                              void* d_out, int out_size, void* d_ws, size_t ws_size,
                              hipStream_t stream) {
  (void)in_sizes; (void)n_in; (void)out_size; (void)ws_size;
  const float* x  = (const float*)d_in[0];
  const float* Wq = (const float*)d_in[1];
  const float* Wk = (const float*)d_in[2];
  const float* Wv = (const float*)d_in[3];
  const float* Wo = (const float*)d_in[4];
  const float* qw = (const float*)d_in[5];
  const float* kw = (const float*)d_in[6];
  float* out = (float*)d_out;

  char* p = (char*)d_ws;
  u16* xb    = (u16*)p;   p += (size_t)4096 * 1024 * 2;
  u16* WqkvT = (u16*)p;   p += (size_t)1536 * 1024 * 2;
  u16* WoT   = (u16*)p;   p += (size_t)1024 * 1024 * 2;
  float* qkv = (float*)p; p += (size_t)4096 * 1536 * 4;
  u16* Qn    = (u16*)p;   p += (size_t)2 * 16 * 2048 * 64 * 2;
  u16* Kn    = (u16*)p;   p += (size_t)2 * 4 * 2048 * 64 * 2;
  u16* Vt    = (u16*)p;   p += (size_t)2 * 4 * 64 * 2048 * 2;
  u16* AO    = (u16*)p;   p += (size_t)4096 * 1024 * 2;

  cast_x_kernel<<<2048, 256, 0, stream>>>(x, xb, 4096 * 1024);
  wtrans_kernel<<<dim3(16, 16), 256, 0, stream>>>(Wq, WqkvT, 1024, 0);
  wtrans_kernel<<<dim3(4, 16), 256, 0, stream>>>(Wk, WqkvT, 256, 1024);
  wtrans_kernel<<<dim3(4, 16), 256, 0, stream>>>(Wv, WqkvT, 256, 1280);
  wtrans_kernel<<<dim3(16, 16), 256, 0, stream>>>(Wo, WoT, 1024, 0);
  gemm_bt_kernel<<<dim3(12, 32), 256, 0, stream>>>(xb, WqkvT, qkv, 4096, 1536, 1024);
  qknorm_kernel<<<20480, 256, 0, stream>>>(qkv, qw, kw, Qn, Kn, Vt);
  attn_kernel<<<1024, 256, 0, stream>>>(Qn, Kn, Vt, AO);
  gemm_bt_kernel<<<dim3(8, 32), 256, 0, stream>>>(AO, WoT, out, 4096, 1024, 1024);
}

// Round 2
// 238.915 us; speedup vs baseline: 1.6074x; 1.6074x over previous
//
#include <hip/hip_runtime.h>
#include <stdint.h>

typedef unsigned short u16;
typedef __attribute__((ext_vector_type(8))) short short8;
typedef __attribute__((ext_vector_type(4))) float f32x4;
typedef __attribute__((ext_vector_type(8))) u16 u16x8;

#define LOG2E 1.4426950408889634f
// 2*SCALE/SOFT_CAP*log2(e) = 2*0.125/50*log2(e)
#define CEXP2 0.0072134752044448f

static __device__ __forceinline__ u16 f2bf(float f) {
  union { float f; unsigned u; } v; v.f = f;
  unsigned r = v.u + 0x7fffu + ((v.u >> 16) & 1u);
  return (u16)(r >> 16);
}

static __device__ __forceinline__ void gload16(const void* g, void* l) {
  __builtin_amdgcn_global_load_lds(
      (const __attribute__((address_space(1))) void*)g,
      (__attribute__((address_space(3))) void*)l, 16, 0, 0);
}

// ---------------- cast x fp32 -> bf16 ----------------
__global__ void __launch_bounds__(256) cast_x_kernel(const float* __restrict__ x,
                                                     u16* __restrict__ xb, int n) {
  int i = (blockIdx.x * 256 + threadIdx.x) * 8;
  if (i >= n) return;
  f32x4 a = *(const f32x4*)(x + i);
  f32x4 b = *(const f32x4*)(x + i + 4);
  u16x8 o;
  o[0] = f2bf(a[0]); o[1] = f2bf(a[1]); o[2] = f2bf(a[2]); o[3] = f2bf(a[3]);
  o[4] = f2bf(b[0]); o[5] = f2bf(b[1]); o[6] = f2bf(b[2]); o[7] = f2bf(b[3]);
  *(u16x8*)(xb + i) = o;
}

// ------- transpose+cast weight: W (1024 x ncols) fp32 -> WT bf16, WT[row_off+n][k] -------
__global__ void __launch_bounds__(256) wtrans_kernel(const float* __restrict__ W,
                                                     u16* __restrict__ WT,
                                                     int ncols, int row_off) {
  __shared__ u16 tile[64][68];
  int c0 = blockIdx.x * 64;
  int r0 = blockIdx.y * 64;
  int cc = threadIdx.x & 63, rb = threadIdx.x >> 6;
#pragma unroll
  for (int i = 0; i < 16; i++) {
    int r = rb + i * 4;
    tile[r][cc] = f2bf(W[(size_t)(r0 + r) * ncols + c0 + cc]);
  }
  __syncthreads();
#pragma unroll
  for (int i = 0; i < 16; i++) {
    int n = rb + i * 4;
    WT[(size_t)(row_off + c0 + n) * 1024 + r0 + cc] = tile[cc][n];
  }
}

// ---------------- GEMM: C(MxN) fp32 = A(MxK) bf16 @ Bt(NxK)^T bf16 ----------------
__global__ void __launch_bounds__(256) gemm_bt_kernel(const u16* __restrict__ A,
                                                      const u16* __restrict__ Bt,
                                                      float* __restrict__ C,
                                                      int M, int N, int K) {
  __shared__ __align__(16) u16 ldsA[128 * 64];
  __shared__ __align__(16) u16 ldsB[128 * 64];
  int tid = threadIdx.x;
  int l = tid & 63, w = tid >> 6;
  int wm = w >> 1, wn = w & 1;
  int fr = l & 15, fg = l >> 4;
  int m0 = blockIdx.y * 128, n0 = blockIdx.x * 128;
  f32x4 acc[4][4];
#pragma unroll
  for (int i = 0; i < 4; i++)
#pragma unroll
    for (int j = 0; j < 4; j++) acc[i][j] = (f32x4)(0.0f);

  int lrow = l >> 3;
  int lcol = (l & 7) * 8;
  for (int k0 = 0; k0 < K; k0 += 64) {
#pragma unroll
    for (int i = 0; i < 4; i++) {
      int ci = w * 4 + i;
      gload16(A + (size_t)(m0 + ci * 8 + lrow) * K + k0 + lcol, ldsA + ci * 512);
      gload16(Bt + (size_t)(n0 + ci * 8 + lrow) * K + k0 + lcol, ldsB + ci * 512);
    }
    __syncthreads();
#pragma unroll
    for (int ks = 0; ks < 2; ks++) {
      short8 av[4], bv[4];
#pragma unroll
      for (int mb = 0; mb < 4; mb++)
        av[mb] = *(const short8*)(ldsA + (wm * 64 + mb * 16 + fr) * 64 + ks * 32 + fg * 8);
#pragma unroll
      for (int nb = 0; nb < 4; nb++)
        bv[nb] = *(const short8*)(ldsB + (wn * 64 + nb * 16 + fr) * 64 + ks * 32 + fg * 8);
#pragma unroll
      for (int mb = 0; mb < 4; mb++)
#pragma unroll
        for (int nb = 0; nb < 4; nb++)
          acc[mb][nb] = __builtin_amdgcn_mfma_f32_16x16x32_bf16(av[mb], bv[nb], acc[mb][nb], 0, 0, 0);
    }
    __syncthreads();
  }
#pragma unroll
  for (int mb = 0; mb < 4; mb++)
#pragma unroll
    for (int nb = 0; nb < 4; nb++)
#pragma unroll
      for (int r = 0; r < 4; r++)
        C[(size_t)(m0 + wm * 64 + mb * 16 + fg * 4 + r) * N + (n0 + wn * 64 + nb * 16 + fr)] =
            acc[mb][nb][r];
}

// ---------------- QKNorm: qkv fp32 [4096][1536] -> Qn/Kn bf16 ----------------
__global__ void __launch_bounds__(256) qknorm_kernel(const float* __restrict__ qkv,
                                                     const float* __restrict__ qw,
                                                     const float* __restrict__ kw,
                                                     u16* __restrict__ Qn,
                                                     u16* __restrict__ Kn) {
  int task = blockIdx.x * 4 + (threadIdx.x >> 6);
  int d = threadIdx.x & 63;
  int tf = task / 20, slot = task - (task / 20) * 20;
  int b = tf >> 11, t = tf & 2047;
  if (slot < 16) {
    float v = qkv[(size_t)tf * 1536 + slot * 64 + d];
    float ss = v * v;
#pragma unroll
    for (int m = 32; m >= 1; m >>= 1) ss += __shfl_xor(ss, m, 64);
    float rn = rsqrtf(ss * (1.0f / 64.0f) + 1e-6f);
    Qn[(size_t)((b * 16 + slot) * 2048 + t) * 64 + d] = f2bf(v * rn * qw[d]);
  } else {
    int kv = slot - 16;
    float v = qkv[(size_t)tf * 1536 + 1024 + kv * 64 + d];
    float ss = v * v;
#pragma unroll
    for (int m = 32; m >= 1; m >>= 1) ss += __shfl_xor(ss, m, 64);
    float rn = rsqrtf(ss * (1.0f / 64.0f) + 1e-6f);
    Kn[(size_t)((b * 4 + kv) * 2048 + t) * 64 + d] = f2bf(v * rn * kw[d]);
  }
}

// ---------------- V transpose (LDS-tiled, coalesced both sides) ----------------
__global__ void __launch_bounds__(256) vtrans_kernel(const float* __restrict__ qkv,
                                                     u16* __restrict__ Vt) {
  __shared__ u16 tile[64][68];
  int bkv = blockIdx.y;  // b*4+kv
  int t0 = blockIdx.x * 64;
  int b = bkv >> 2, kv = bkv & 3;
  int cc = threadIdx.x & 63, rb = threadIdx.x >> 6;
#pragma unroll
  for (int i = 0; i < 16; i++) {
    int tt = rb + i * 4;
    tile[tt][cc] = f2bf(qkv[(size_t)(b * 2048 + t0 + tt) * 1536 + 1280 + kv * 64 + cc]);
  }
  __syncthreads();
#pragma unroll
  for (int i = 0; i < 16; i++) {
    int d = rb + i * 4;
    Vt[(size_t)(bkv * 64 + d) * 2048 + t0 + cc] = tile[cc][d];
  }
}

// ---------------- Flash attention: 8 waves, 128-row q-tile, LDS-staged KV ----------------
// K/V staged via global_load_lds with pre-swizzled source: LDS row r (128B), 16B col
// block c stores global col block c^(r&7). Read applies same XOR -> conflict-free b128.
static __device__ __forceinline__ void stage_kv(const u16* Kb, const u16* Vb,
                                                u16* dstK, int kb0, int sr, int sc) {
  gload16(Kb + (size_t)(kb0 + sr) * 64 + sc, dstK);
  gload16(Vb + (size_t)sr * 2048 + kb0 + sc, dstK + 4096);
}

__global__ void __launch_bounds__(512) attn_kernel(const u16* __restrict__ Qn,
                                                   const u16* __restrict__ Kn,
                                                   const u16* __restrict__ Vt,
                                                   u16* __restrict__ AO) {
  __shared__ __align__(16) u16 ldsKV[2][8192];  // [buf][K:4096 | V:4096]
  __shared__ __align__(16) u16 plds[8][16][72];
  int tid = threadIdx.x;
  int w = tid >> 6, l = tid & 63;
  int fr = l & 15, fg = l >> 4;
  int head = blockIdx.x & 31;                 // 32 (b,h) heads
  int qtile = 15 - (blockIdx.x >> 5);         // heavy tiles launch first
  int b = head >> 4, h = head & 15;
  int kvh = h >> 2;
  const u16* Qb = Qn + (size_t)((b * 16 + h) * 2048) * 64;
  const u16* Kb = Kn + (size_t)((b * 4 + kvh) * 2048) * 64;
  const u16* Vb = Vt + (size_t)((b * 4 + kvh) * 64) * 2048;
  int qt0 = qtile * 128 + w * 16;

  short8 qf[2];
#pragma unroll
  for (int ks = 0; ks < 2; ks++)
    qf[ks] = *(const short8*)(Qb + (size_t)(qt0 + fr) * 64 + ks * 32 + fg * 8);

  f32x4 of[4];
#pragma unroll
  for (int i = 0; i < 4; i++) of[i] = (f32x4)(0.0f);
  float mrow[4] = {-1e30f, -1e30f, -1e30f, -1e30f};
  float lsum[4] = {0.0f, 0.0f, 0.0f, 0.0f};
  u16(*P)[72] = plds[w];

  int sr = tid >> 3;                       // staged row 0..63
  int sc = ((tid & 7) ^ (sr & 7)) * 8;     // pre-swizzled source col (elems)
  int nt = 2 * qtile + 2;

  stage_kv(Kb, Vb, &ldsKV[0][w * 512], 0, sr, sc);

  for (int t = 0; t < nt; t++) {
    const u16* kbuf = ldsKV[t & 1];
    const u16* vbuf = kbuf + 4096;
    if (t + 1 < nt) {
      stage_kv(Kb, Vb, &ldsKV[(t + 1) & 1][w * 512], (t + 1) * 64, sr, sc);
      asm volatile("s_waitcnt vmcnt(2)" ::: "memory");
    } else {
      asm volatile("s_waitcnt vmcnt(0)" ::: "memory");
    }
    __builtin_amdgcn_s_barrier();
    asm volatile("" ::: "memory");

    int kb0 = t * 64;
    if (kb0 <= qt0 + 15) {  // wave-uniform: skip fully-masked tiles
      f32x4 sf[4];
#pragma unroll
      for (int kb = 0; kb < 4; kb++) sf[kb] = (f32x4)(0.0f);
      __builtin_amdgcn_s_setprio(1);
#pragma unroll
      for (int ks = 0; ks < 2; ks++) {
#pragma unroll
        for (int kb = 0; kb < 4; kb++) {
          short8 kf = *(const short8*)(kbuf + (kb * 16 + fr) * 64 +
                                       ((((ks << 2) + fg) ^ (fr & 7)) << 3));
          sf[kb] = __builtin_amdgcn_mfma_f32_16x16x32_bf16(qf[ks], kf, sf[kb], 0, 0, 0);
        }
      }
      __builtin_amdgcn_s_setprio(0);
      // soft cap: 50*tanh(s*SCALE/50) = 50 - 100/(exp2(s*CEXP2)+1)
#pragma unroll
      for (int kb = 0; kb < 4; kb++)
#pragma unroll
        for (int r = 0; r < 4; r++) {
          float e = __builtin_amdgcn_exp2f(sf[kb][r] * CEXP2);
          sf[kb][r] = 50.0f - 100.0f * __builtin_amdgcn_rcpf(e + 1.0f);
        }
      if (kb0 + 63 > qt0) {  // diagonal tiles: causal mask
#pragma unroll
        for (int kb = 0; kb < 4; kb++)
#pragma unroll
          for (int r = 0; r < 4; r++)
            if (kb0 + kb * 16 + fr > qt0 + fg * 4 + r) sf[kb][r] = -1e30f;
      }
      // online softmax: row q=fg*4+r, cols across (kb, fr); reduce over low-4 lane bits
#pragma unroll
      for (int r = 0; r < 4; r++) {
        float mx = fmaxf(fmaxf(sf[0][r], sf[1][r]), fmaxf(sf[2][r], sf[3][r]));
        mx = fmaxf(mx, __shfl_xor(mx, 1, 64));
        mx = fmaxf(mx, __shfl_xor(mx, 2, 64));
        mx = fmaxf(mx, __shfl_xor(mx, 4, 64));
        mx = fmaxf(mx, __shfl_xor(mx, 8, 64));
        float mnew = fmaxf(mrow[r], mx);
        float alpha = __builtin_amdgcn_exp2f((mrow[r] - mnew) * LOG2E);
        mrow[r] = mnew;
        float rs = 0.0f;
#pragma unroll
        for (int kb = 0; kb < 4; kb++) {
          float pf = __builtin_amdgcn_exp2f((sf[kb][r] - mnew) * LOG2E);
          sf[kb][r] = pf;
          rs += pf;
        }
        rs += __shfl_xor(rs, 1, 64);
        rs += __shfl_xor(rs, 2, 64);
        rs += __shfl_xor(rs, 4, 64);
        rs += __shfl_xor(rs, 8, 64);
        lsum[r] = lsum[r] * alpha + rs;
#pragma unroll
        for (int db = 0; db < 4; db++) of[db][r] *= alpha;
      }
      // P (C-frag) -> wave-private LDS -> A-frag
#pragma unroll
      for (int kb = 0; kb < 4; kb++)
#pragma unroll
        for (int r = 0; r < 4; r++)
          P[fg * 4 + r][kb * 16 + fr] = f2bf(sf[kb][r]);
      short8 pa[2];
#pragma unroll
      for (int ks = 0; ks < 2; ks++)
        pa[ks] = *(const short8*)(&P[fr][ks * 32 + fg * 8]);
      __builtin_amdgcn_s_setprio(1);
#pragma unroll
      for (int ks = 0; ks < 2; ks++)
#pragma unroll
        for (int db = 0; db < 4; db++) {
          short8 vf = *(const short8*)(vbuf + (db * 16 + fr) * 64 +
                                       ((((ks << 2) + fg) ^ (fr & 7)) << 3));
          of[db] = __builtin_amdgcn_mfma_f32_16x16x32_bf16(pa[ks], vf, of[db], 0, 0, 0);
        }
      __builtin_amdgcn_s_setprio(0);
    }
    asm volatile("" ::: "memory");
    __builtin_amdgcn_s_barrier();
  }
#pragma unroll
  for (int r = 0; r < 4; r++) lsum[r] = __builtin_amdgcn_rcpf(lsum[r]);
#pragma unroll
  for (int db = 0; db < 4; db++)
#pragma unroll
    for (int r = 0; r < 4; r++)
      AO[(size_t)(b * 2048 + qt0 + fg * 4 + r) * 1024 + h * 64 + db * 16 + fr] =
          f2bf(of[db][r] * lsum[r]);
}

extern "C" void kernel_launch(void* const* d_in, const int* in_sizes, int n_in,
                              void* d_out, int out_size, void* d_ws, size_t ws_size,
                              hipStream_t stream) {
  (void)in_sizes; (void)n_in; (void)out_size; (void)ws_size;
  const float* x  = (const float*)d_in[0];
  const float* Wq = (const float*)d_in[1];
  const float* Wk = (const float*)d_in[2];
  const float* Wv = (const float*)d_in[3];
  const float* Wo = (const float*)d_in[4];
  const float* qw = (const float*)d_in[5];
  const float* kw = (const float*)d_in[6];
  float* out = (float*)d_out;

  char* p = (char*)d_ws;
  u16* xb    = (u16*)p;   p += (size_t)4096 * 1024 * 2;
  u16* WqkvT = (u16*)p;   p += (size_t)1536 * 1024 * 2;
  u16* WoT   = (u16*)p;   p += (size_t)1024 * 1024 * 2;
  float* qkv = (float*)p; p += (size_t)4096 * 1536 * 4;
  u16* Qn    = (u16*)p;   p += (size_t)2 * 16 * 2048 * 64 * 2;
  u16* Kn    = (u16*)p;   p += (size_t)2 * 4 * 2048 * 64 * 2;
  u16* Vt    = (u16*)p;   p += (size_t)2 * 4 * 64 * 2048 * 2;
  u16* AO    = (u16*)p;   p += (size_t)4096 * 1024 * 2;

  cast_x_kernel<<<2048, 256, 0, stream>>>(x, xb, 4096 * 1024);
  wtrans_kernel<<<dim3(16, 16), 256, 0, stream>>>(Wq, WqkvT, 1024, 0);
  wtrans_kernel<<<dim3(4, 16), 256, 0, stream>>>(Wk, WqkvT, 256, 1024);
  wtrans_kernel<<<dim3(4, 16), 256, 0, stream>>>(Wv, WqkvT, 256, 1280);
  wtrans_kernel<<<dim3(16, 16), 256, 0, stream>>>(Wo, WoT, 1024, 0);
  gemm_bt_kernel<<<dim3(12, 32), 256, 0, stream>>>(xb, WqkvT, qkv, 4096, 1536, 1024);
  qknorm_kernel<<<20480, 256, 0, stream>>>(qkv, qw, kw, Qn, Kn);
  vtrans_kernel<<<dim3(32, 8), 256, 0, stream>>>(qkv, Vt);
  attn_kernel<<<512, 512, 0, stream>>>(Qn, Kn, Vt, AO);
  gemm_bt_kernel<<<dim3(8, 32), 256, 0, stream>>>(AO, WoT, out, 4096, 1024, 1024);
}

// Round 3
// 201.361 us; speedup vs baseline: 1.9071x; 1.1865x over previous
//
#include <hip/hip_runtime.h>
#include <stdint.h>

typedef unsigned short u16;
typedef __attribute__((ext_vector_type(8))) short short8;
typedef __attribute__((ext_vector_type(4))) float f32x4;
typedef __attribute__((ext_vector_type(8))) u16 u16x8;

#define LOG2E 1.4426950408889634f
// 2*SCALE/SOFT_CAP = 2*0.125/50 ; times log2(e)
#define CEXP2 0.0072134752044448f
#define C1L 72.13475204444817f    // 50*log2(e)
#define C2L 144.26950408889634f   // 100*log2(e)

static __device__ __forceinline__ u16 f2bf(float f) {
  union { float f; unsigned u; } v; v.f = f;
  unsigned r = v.u + 0x7fffu + ((v.u >> 16) & 1u);
  return (u16)(r >> 16);
}

static __device__ __forceinline__ void gload16(const void* g, void* l) {
  __builtin_amdgcn_global_load_lds(
      (const __attribute__((address_space(1))) void*)g,
      (__attribute__((address_space(3))) void*)l, 16, 0, 0);
}

// ---------------- cast x fp32 -> bf16 ----------------
__global__ void __launch_bounds__(256) cast_x_kernel(const float* __restrict__ x,
                                                     u16* __restrict__ xb, int n) {
  int i = (blockIdx.x * 256 + threadIdx.x) * 8;
  if (i >= n) return;
  f32x4 a = *(const f32x4*)(x + i);
  f32x4 b = *(const f32x4*)(x + i + 4);
  u16x8 o;
  o[0] = f2bf(a[0]); o[1] = f2bf(a[1]); o[2] = f2bf(a[2]); o[3] = f2bf(a[3]);
  o[4] = f2bf(b[0]); o[5] = f2bf(b[1]); o[6] = f2bf(b[2]); o[7] = f2bf(b[3]);
  *(u16x8*)(xb + i) = o;
}

// ------- all 4 weight transposes in one launch -------
__global__ void __launch_bounds__(256) wtrans_all_kernel(const float* __restrict__ Wq,
                                                         const float* __restrict__ Wk,
                                                         const float* __restrict__ Wv,
                                                         const float* __restrict__ Wo,
                                                         u16* __restrict__ WqkvT,
                                                         u16* __restrict__ WoT) {
  __shared__ u16 tile[64][68];
  int id = blockIdx.x;
  const float* W; u16* WT; int ncols, row_off, cx, ry;
  if (id < 256)      { W = Wq; WT = WqkvT; ncols = 1024; row_off = 0;    cx = id & 15;        ry = id >> 4; }
  else if (id < 320) { W = Wk; WT = WqkvT; ncols = 256;  row_off = 1024; cx = (id - 256) & 3; ry = (id - 256) >> 2; }
  else if (id < 384) { W = Wv; WT = WqkvT; ncols = 256;  row_off = 1280; cx = (id - 320) & 3; ry = (id - 320) >> 2; }
  else               { W = Wo; WT = WoT;   ncols = 1024; row_off = 0;    cx = (id - 384) & 15; ry = (id - 384) >> 4; }
  int c0 = cx * 64, r0 = ry * 64;
  int cc = threadIdx.x & 63, rb = threadIdx.x >> 6;
#pragma unroll
  for (int i = 0; i < 16; i++) {
    int r = rb + i * 4;
    tile[r][cc] = f2bf(W[(size_t)(r0 + r) * ncols + c0 + cc]);
  }
  __syncthreads();
#pragma unroll
  for (int i = 0; i < 16; i++) {
    int n = rb + i * 4;
    WT[(size_t)(row_off + c0 + n) * 1024 + r0 + cc] = tile[cc][n];
  }
}

// ---------------- QKV GEMM with fused QKNorm epilogue ----------------
// C(4096x1536) = xb(4096x1024) @ WqkvT^T. Cols 0..1023 -> Q (RMSNorm*qw -> Qn bf16),
// 1024..1279 -> K (RMSNorm*kw -> Kn bf16), 1280..1535 -> V (bf16 -> Vc row-major).
__global__ void __launch_bounds__(256) gemm_qkv_kernel(const u16* __restrict__ A,
                                                       const u16* __restrict__ Bt,
                                                       const float* __restrict__ qw,
                                                       const float* __restrict__ kw,
                                                       u16* __restrict__ Qn,
                                                       u16* __restrict__ Kn,
                                                       u16* __restrict__ Vc) {
  __shared__ __align__(16) u16 ldsA[128 * 64];
  __shared__ __align__(16) u16 ldsB[128 * 64];
  const int K = 1024;
  int tid = threadIdx.x;
  int l = tid & 63, w = tid >> 6;
  int wm = w >> 1, wn = w & 1;
  int fr = l & 15, fg = l >> 4;
  int m0 = blockIdx.y * 128, n0 = blockIdx.x * 128;
  f32x4 acc[4][4];
#pragma unroll
  for (int i = 0; i < 4; i++)
#pragma unroll
    for (int j = 0; j < 4; j++) acc[i][j] = (f32x4)(0.0f);

  int lrow = l >> 3;
  int lcol = (l & 7) * 8;
  for (int k0 = 0; k0 < K; k0 += 64) {
#pragma unroll
    for (int i = 0; i < 4; i++) {
      int ci = w * 4 + i;
      gload16(A + (size_t)(m0 + ci * 8 + lrow) * K + k0 + lcol, ldsA + ci * 512);
      gload16(Bt + (size_t)(n0 + ci * 8 + lrow) * K + k0 + lcol, ldsB + ci * 512);
    }
    __syncthreads();
#pragma unroll
    for (int ks = 0; ks < 2; ks++) {
      short8 av[4], bv[4];
#pragma unroll
      for (int mb = 0; mb < 4; mb++)
        av[mb] = *(const short8*)(ldsA + (wm * 64 + mb * 16 + fr) * 64 + ks * 32 + fg * 8);
#pragma unroll
      for (int nb = 0; nb < 4; nb++)
        bv[nb] = *(const short8*)(ldsB + (wn * 64 + nb * 16 + fr) * 64 + ks * 32 + fg * 8);
#pragma unroll
      for (int mb = 0; mb < 4; mb++)
#pragma unroll
        for (int nb = 0; nb < 4; nb++)
          acc[mb][nb] = __builtin_amdgcn_mfma_f32_16x16x32_bf16(av[mb], bv[nb], acc[mb][nb], 0, 0, 0);
    }
    __syncthreads();
  }

  int hc = n0 + wn * 64;       // this wave's 64-col group = exactly one head
  int m_base = m0 + wm * 64;
  if (hc < 1280) {
    const float* wptr = (hc < 1024) ? qw : kw;
    float wv[4];
#pragma unroll
    for (int nb = 0; nb < 4; nb++) wv[nb] = wptr[nb * 16 + fr];
#pragma unroll
    for (int mb = 0; mb < 4; mb++)
#pragma unroll
      for (int r = 0; r < 4; r++) {
        float ss = acc[mb][0][r] * acc[mb][0][r] + acc[mb][1][r] * acc[mb][1][r] +
                   acc[mb][2][r] * acc[mb][2][r] + acc[mb][3][r] * acc[mb][3][r];
        ss += __shfl_xor(ss, 1, 64);
        ss += __shfl_xor(ss, 2, 64);
        ss += __shfl_xor(ss, 4, 64);
        ss += __shfl_xor(ss, 8, 64);
        float rn = rsqrtf(ss * (1.0f / 64.0f) + 1e-6f);
        int row = m_base + mb * 16 + fg * 4 + r;
        int b = row >> 11, t = row & 2047;
        size_t base;
        u16* dst;
        if (hc < 1024) { dst = Qn; base = ((size_t)(b * 16 + (hc >> 6)) * 2048 + t) * 64; }
        else           { dst = Kn; base = ((size_t)(b * 4 + ((hc - 1024) >> 6)) * 2048 + t) * 64; }
#pragma unroll
        for (int nb = 0; nb < 4; nb++)
          dst[base + nb * 16 + fr] = f2bf(acc[mb][nb][r] * rn * wv[nb]);
      }
  } else {
    int kv = (hc - 1280) >> 6;
#pragma unroll
    for (int mb = 0; mb < 4; mb++)
#pragma unroll
      for (int r = 0; r < 4; r++) {
        int row = m_base + mb * 16 + fg * 4 + r;
        int b = row >> 11, t = row & 2047;
        size_t base = ((size_t)(b * 4 + kv) * 2048 + t) * 64;
#pragma unroll
        for (int nb = 0; nb < 4; nb++)
          Vc[base + nb * 16 + fr] = f2bf(acc[mb][nb][r]);
      }
  }
}

// ---------------- plain GEMM (out-proj): C fp32 = A bf16 @ Bt^T ----------------
__global__ void __launch_bounds__(256) gemm_bt_kernel(const u16* __restrict__ A,
                                                      const u16* __restrict__ Bt,
                                                      float* __restrict__ C,
                                                      int M, int N, int K) {
  __shared__ __align__(16) u16 ldsA[128 * 64];
  __shared__ __align__(16) u16 ldsB[128 * 64];
  int tid = threadIdx.x;
  int l = tid & 63, w = tid >> 6;
  int wm = w >> 1, wn = w & 1;
  int fr = l & 15, fg = l >> 4;
  int m0 = blockIdx.y * 128, n0 = blockIdx.x * 128;
  f32x4 acc[4][4];
#pragma unroll
  for (int i = 0; i < 4; i++)
#pragma unroll
    for (int j = 0; j < 4; j++) acc[i][j] = (f32x4)(0.0f);

  int lrow = l >> 3;
  int lcol = (l & 7) * 8;
  for (int k0 = 0; k0 < K; k0 += 64) {
#pragma unroll
    for (int i = 0; i < 4; i++) {
      int ci = w * 4 + i;
      gload16(A + (size_t)(m0 + ci * 8 + lrow) * K + k0 + lcol, ldsA + ci * 512);
      gload16(Bt + (size_t)(n0 + ci * 8 + lrow) * K + k0 + lcol, ldsB + ci * 512);
    }
    __syncthreads();
#pragma unroll
    for (int ks = 0; ks < 2; ks++) {
      short8 av[4], bv[4];
#pragma unroll
      for (int mb = 0; mb < 4; mb++)
        av[mb] = *(const short8*)(ldsA + (wm * 64 + mb * 16 + fr) * 64 + ks * 32 + fg * 8);
#pragma unroll
      for (int nb = 0; nb < 4; nb++)
        bv[nb] = *(const short8*)(ldsB + (wn * 64 + nb * 16 + fr) * 64 + ks * 32 + fg * 8);
#pragma unroll
      for (int mb = 0; mb < 4; mb++)
#pragma unroll
        for (int nb = 0; nb < 4; nb++)
          acc[mb][nb] = __builtin_amdgcn_mfma_f32_16x16x32_bf16(av[mb], bv[nb], acc[mb][nb], 0, 0, 0);
    }
    __syncthreads();
  }
#pragma unroll
  for (int mb = 0; mb < 4; mb++)
#pragma unroll
    for (int nb = 0; nb < 4; nb++)
#pragma unroll
      for (int r = 0; r < 4; r++)
        C[(size_t)(m0 + wm * 64 + mb * 16 + fg * 4 + r) * N + (n0 + wn * 64 + nb * 16 + fr)] =
            acc[mb][nb][r];
}

// ---------------- V transpose bf16 -> Vt[d][t] ----------------
__global__ void __launch_bounds__(256) vtrans_kernel(const u16* __restrict__ Vc,
                                                     u16* __restrict__ Vt) {
  __shared__ u16 tile[64][68];
  int bkv = blockIdx.y;
  int t0 = blockIdx.x * 64;
  int cc = threadIdx.x & 63, rb = threadIdx.x >> 6;
#pragma unroll
  for (int i = 0; i < 16; i++) {
    int tt = rb + i * 4;
    tile[tt][cc] = Vc[(size_t)(bkv * 2048 + t0 + tt) * 64 + cc];
  }
  __syncthreads();
#pragma unroll
  for (int i = 0; i < 16; i++) {
    int d = rb + i * 4;
    Vt[(size_t)(bkv * 64 + d) * 2048 + t0 + cc] = tile[cc][d];
  }
}

// ---------------- Flash attention: swapped QK^T, lane-local softmax ----------------
static __device__ __forceinline__ void stage_kv(const u16* Kb, const u16* Vb,
                                                u16* dstK, int kb0, int sr, int sc) {
  gload16(Kb + (size_t)(kb0 + sr) * 64 + sc, dstK);
  gload16(Vb + (size_t)sr * 2048 + kb0 + sc, dstK + 4096);
}

__global__ void __launch_bounds__(512) attn_kernel(const u16* __restrict__ Qn,
                                                   const u16* __restrict__ Kn,
                                                   const u16* __restrict__ Vt,
                                                   u16* __restrict__ AO) {
  __shared__ __align__(16) u16 ldsKV[2][8192];  // [buf][K:4096 | V:4096]
  __shared__ __align__(16) u16 plds[8][16][80]; // stride 80: 4-way max on b128 reads
  int tid = threadIdx.x;
  int w = tid >> 6, l = tid & 63;
  int fr = l & 15, fg = l >> 4;
  int i = blockIdx.x;
  int head = i & 31;
  // complement pairing: first 256 blocks qtiles 15..8, second 256 qtiles 0..7
  // -> CU pair (i, i+256) always sums to 34 tiles of work
  int qtile = (i < 256) ? (15 - (i >> 5)) : ((i >> 5) - 8);
  int b = head >> 4, h = head & 15;
  int kvh = h >> 2;
  const u16* Qb = Qn + (size_t)((b * 16 + h) * 2048) * 64;
  const u16* Kb = Kn + (size_t)((b * 4 + kvh) * 2048) * 64;
  const u16* Vb = Vt + (size_t)((b * 4 + kvh) * 64) * 2048;
  int qt0 = qtile * 128 + w * 16;

  short8 qf[2];
#pragma unroll
  for (int ks = 0; ks < 2; ks++)
    qf[ks] = *(const short8*)(Qb + (size_t)(qt0 + fr) * 64 + ks * 32 + fg * 8);

  f32x4 of[4];
#pragma unroll
  for (int ii = 0; ii < 4; ii++) of[ii] = (f32x4)(0.0f);
  float mrow = -1e30f, lsum = 0.0f;  // scalar: this lane tracks q = qt0 + fr
  u16(*P)[80] = plds[w];

  int sr = tid >> 3;
  int sc = ((tid & 7) ^ (sr & 7)) * 8;
  int nt = 2 * qtile + 2;

  stage_kv(Kb, Vb, &ldsKV[0][w * 512], 0, sr, sc);

  for (int t = 0; t < nt; t++) {
    const u16* kbuf = ldsKV[t & 1];
    const u16* vbuf = kbuf + 4096;
    if (t + 1 < nt) {
      stage_kv(Kb, Vb, &ldsKV[(t + 1) & 1][w * 512], (t + 1) * 64, sr, sc);
      asm volatile("s_waitcnt vmcnt(2)" ::: "memory");
    } else {
      asm volatile("s_waitcnt vmcnt(0)" ::: "memory");
    }
    __builtin_amdgcn_s_barrier();
    asm volatile("" ::: "memory");

    int kb0 = t * 64;
    if (kb0 <= qt0 + 15) {
      // S^T = K Q^T : sf[kb][r] = S[k = kb0+kb*16+fg*4+r][q = qt0+fr]
      f32x4 sf[4];
#pragma unroll
      for (int kb = 0; kb < 4; kb++) sf[kb] = (f32x4)(0.0f);
      __builtin_amdgcn_s_setprio(1);
#pragma unroll
      for (int ks = 0; ks < 2; ks++) {
#pragma unroll
        for (int kb = 0; kb < 4; kb++) {
          short8 kf = *(const short8*)(kbuf + (kb * 16 + fr) * 64 +
                                       ((((ks << 2) + fg) ^ (fr & 7)) << 3));
          sf[kb] = __builtin_amdgcn_mfma_f32_16x16x32_bf16(kf, qf[ks], sf[kb], 0, 0, 0);
        }
      }
      __builtin_amdgcn_s_setprio(0);
      // soft cap in log2 domain: sl = (50 - 100/(exp2(s*CEXP2)+1)) * log2(e)
#pragma unroll
      for (int kb = 0; kb < 4; kb++)
#pragma unroll
        for (int r = 0; r < 4; r++) {
          float e = __builtin_amdgcn_exp2f(sf[kb][r] * CEXP2);
          sf[kb][r] = C1L - C2L * __builtin_amdgcn_rcpf(e + 1.0f);
        }
      if (kb0 + 63 > qt0) {  // diagonal: causal mask (k > q)
#pragma unroll
        for (int kb = 0; kb < 4; kb++)
#pragma unroll
          for (int r = 0; r < 4; r++)
            if (kb0 + kb * 16 + fg * 4 + r > qt0 + fr) sf[kb][r] = -1e30f;
      }
      // lane-local row stats (16 values for q = fr) + 2 shfl over fg bits
      float pmax = sf[0][0];
#pragma unroll
      for (int kb = 0; kb < 4; kb++)
#pragma unroll
        for (int r = 0; r < 4; r++) pmax = fmaxf(pmax, sf[kb][r]);
      pmax = fmaxf(pmax, __shfl_xor(pmax, 16, 64));
      pmax = fmaxf(pmax, __shfl_xor(pmax, 32, 64));
      float mnew = fmaxf(mrow, pmax);
      float alpha = __builtin_amdgcn_exp2f(mrow - mnew);
      mrow = mnew;
      float rs = 0.0f;
#pragma unroll
      for (int kb = 0; kb < 4; kb++)
#pragma unroll
        for (int r = 0; r < 4; r++) {
          float pf = __builtin_amdgcn_exp2f(sf[kb][r] - mnew);
          sf[kb][r] = pf;
          rs += pf;
        }
      rs += __shfl_xor(rs, 16, 64);
      rs += __shfl_xor(rs, 32, 64);
      lsum = lsum * alpha + rs;
      // O rescale: alpha for q-row fg*4+r lives in lane fr = fg*4+r of own 16-group
#pragma unroll
      for (int r = 0; r < 4; r++) {
        float ar = __shfl(alpha, fg * 4 + r, 16);
#pragma unroll
        for (int db = 0; db < 4; db++) of[db][r] *= ar;
      }
      // pack P -> LDS: P[q = fr][k = kb*16 + fg*4 + {0..3}]
#pragma unroll
      for (int kb = 0; kb < 4; kb++)
#pragma unroll
        for (int rp = 0; rp < 2; rp++) {
          unsigned pk;
          asm("v_cvt_pk_bf16_f32 %0, %1, %2" : "=v"(pk)
              : "v"(sf[kb][2 * rp]), "v"(sf[kb][2 * rp + 1]));
          *(unsigned*)(&P[fr][kb * 16 + fg * 4 + 2 * rp]) = pk;
        }
      short8 pa[2];
#pragma unroll
      for (int ks = 0; ks < 2; ks++)
        pa[ks] = *(const short8*)(&P[fr][ks * 32 + fg * 8]);
      __builtin_amdgcn_s_setprio(1);
#pragma unroll
      for (int ks = 0; ks < 2; ks++)
#pragma unroll
        for (int db = 0; db < 4; db++) {
          short8 vf = *(const short8*)(vbuf + (db * 16 + fr) * 64 +
                                       ((((ks << 2) + fg) ^ (fr & 7)) << 3));
          of[db] = __builtin_amdgcn_mfma_f32_16x16x32_bf16(pa[ks], vf, of[db], 0, 0, 0);
        }
      __builtin_amdgcn_s_setprio(0);
    }
    asm volatile("" ::: "memory");
    __builtin_amdgcn_s_barrier();
  }
  float linv = __builtin_amdgcn_rcpf(lsum);
#pragma unroll
  for (int r = 0; r < 4; r++) {
    float li = __shfl(linv, fg * 4 + r, 16);
#pragma unroll
    for (int db = 0; db < 4; db++)
      AO[(size_t)(b * 2048 + qt0 + fg * 4 + r) * 1024 + h * 64 + db * 16 + fr] =
          f2bf(of[db][r] * li);
  }
}

extern "C" void kernel_launch(void* const* d_in, const int* in_sizes, int n_in,
                              void* d_out, int out_size, void* d_ws, size_t ws_size,
                              hipStream_t stream) {
  (void)in_sizes; (void)n_in; (void)out_size; (void)ws_size;
  const float* x  = (const float*)d_in[0];
  const float* Wq = (const float*)d_in[1];
  const float* Wk = (const float*)d_in[2];
  const float* Wv = (const float*)d_in[3];
  const float* Wo = (const float*)d_in[4];
  const float* qw = (const float*)d_in[5];
  const float* kw = (const float*)d_in[6];
  float* out = (float*)d_out;

  char* p = (char*)d_ws;
  u16* xb    = (u16*)p;   p += (size_t)4096 * 1024 * 2;
  u16* WqkvT = (u16*)p;   p += (size_t)1536 * 1024 * 2;
  u16* WoT   = (u16*)p;   p += (size_t)1024 * 1024 * 2;
  u16* Qn    = (u16*)p;   p += (size_t)2 * 16 * 2048 * 64 * 2;
  u16* Kn    = (u16*)p;   p += (size_t)2 * 4 * 2048 * 64 * 2;
  u16* Vc    = (u16*)p;   p += (size_t)2 * 4 * 2048 * 64 * 2;
  u16* Vt    = (u16*)p;   p += (size_t)2 * 4 * 64 * 2048 * 2;
  u16* AO    = (u16*)p;   p += (size_t)4096 * 1024 * 2;

  cast_x_kernel<<<2048, 256, 0, stream>>>(x, xb, 4096 * 1024);
  wtrans_all_kernel<<<640, 256, 0, stream>>>(Wq, Wk, Wv, Wo, WqkvT, WoT);
  gemm_qkv_kernel<<<dim3(12, 32), 256, 0, stream>>>(xb, WqkvT, qw, kw, Qn, Kn, Vc);
  vtrans_kernel<<<dim3(32, 8), 256, 0, stream>>>(Vc, Vt);
  attn_kernel<<<512, 512, 0, stream>>>(Qn, Kn, Vt, AO);
  gemm_bt_kernel<<<dim3(8, 32), 256, 0, stream>>>(AO, WoT, out, 4096, 1024, 1024);
}